// Round 11
// baseline (227.118 us; speedup 1.0000x reference)
//
#include <hip/hip_runtime.h>
#include <math.h>

#define BB 64
#define DD 512
#define MM 8192
#define K2T 512   // scan threads (8 waves)
#define K2C 16    // MM / K2T cold columns per thread (4 float4)

typedef unsigned long long u64;

// ---------------- DPP wave-64 primitives ----------------
template<int CTRL>
__device__ __forceinline__ float dpp_addf(float x) {
    int y = __builtin_amdgcn_update_dpp(0, __float_as_int(x), CTRL, 0xF, 0xF, true);
    return x + __int_as_float(y);
}
__device__ __forceinline__ float wave_sum64(float x) {
    x = dpp_addf<0x111>(x); x = dpp_addf<0x112>(x); x = dpp_addf<0x114>(x); x = dpp_addf<0x118>(x);
    x = dpp_addf<0x142>(x); x = dpp_addf<0x143>(x);
    return __int_as_float(__builtin_amdgcn_readlane(__float_as_int(x), 63));
}
__device__ __forceinline__ float readlane_f(float v, int l) {
    return __int_as_float(__builtin_amdgcn_readlane(__float_as_int(v), l));
}
template<int CTRL>
__device__ __forceinline__ u64 dpp_min_step(u64 k) {
    unsigned lo = (unsigned)k, hi = (unsigned)(k >> 32);
    unsigned nlo = (unsigned)__builtin_amdgcn_update_dpp((int)0xFFFFFFFFu, (int)lo, CTRL, 0xF, 0xF, false);
    unsigned nhi = (unsigned)__builtin_amdgcn_update_dpp((int)0xFFFFFFFFu, (int)hi, CTRL, 0xF, 0xF, false);
    u64 nk = (((u64)nhi) << 32) | (u64)nlo;
    return nk < k ? nk : k;
}
__device__ __forceinline__ u64 wave_min64_lane63(u64 k) {
    k = dpp_min_step<0x111>(k); k = dpp_min_step<0x112>(k); k = dpp_min_step<0x114>(k);
    k = dpp_min_step<0x118>(k); k = dpp_min_step<0x142>(k); k = dpp_min_step<0x143>(k);
    return k;
}
__device__ __forceinline__ u64 wave_min8(u64 k) {
    k = dpp_min_step<0x111>(k); k = dpp_min_step<0x112>(k); k = dpp_min_step<0x114>(k);
    unsigned lo = (unsigned)__builtin_amdgcn_readlane((int)(unsigned)k, 7);
    unsigned hi = (unsigned)__builtin_amdgcn_readlane((int)(unsigned)(k >> 32), 7);
    return (((u64)hi) << 32) | (u64)lo;
}

// ---------------- KA: block 0 = Gram (G, Pfx); blocks 1..256 = K @ MK0 halves ----------------
struct K0Smem {
    float Ks[BB][129];
    float Gs[BB][BB];
};
struct K1Smem {
    float Ks[64 * 65];
    float Ms[64 * 65];
    float sq[4 * 64];
};
#define KA_SMEM ((sizeof(K0Smem) > sizeof(K1Smem)) ? sizeof(K0Smem) : sizeof(K1Smem))

__global__ __launch_bounds__(256) void ka_gram_s0(const float* __restrict__ K, const float* __restrict__ MK0,
                                                  float* __restrict__ G, float* __restrict__ Pfx,
                                                  float* __restrict__ S0p, float* __restrict__ n2p) {
    __shared__ __align__(16) char blob[KA_SMEM];
    const int tid = threadIdx.x;

    if (blockIdx.x == 0) {
        // ---------- Gram + prefix ----------
        K0Smem* sm = (K0Smem*)blob;
        const int ti = ((tid >> 4) & 15) << 2;   // row base
        const int tj = (tid & 15) << 2;          // col base
        float acc[4][4];
        #pragma unroll
        for (int i = 0; i < 4; ++i)
            #pragma unroll
            for (int j = 0; j < 4; ++j) acc[i][j] = 0.f;
        for (int d0 = 0; d0 < DD; d0 += 128) {
            #pragma unroll
            for (int i = 0; i < 32; ++i) {
                int e = i * 256 + tid; int r = e >> 7, c = e & 127;
                sm->Ks[r][c] = K[r * DD + d0 + c];
            }
            __syncthreads();
            for (int dl = 0; dl < 128; ++dl) {
                float rv[4], cv[4];
                #pragma unroll
                for (int i = 0; i < 4; ++i) rv[i] = sm->Ks[ti + i][dl];
                #pragma unroll
                for (int j = 0; j < 4; ++j) cv[j] = sm->Ks[tj + j][dl];
                #pragma unroll
                for (int i = 0; i < 4; ++i)
                    #pragma unroll
                    for (int j = 0; j < 4; ++j) acc[i][j] += rv[i] * cv[j];
            }
            __syncthreads();
        }
        #pragma unroll
        for (int i = 0; i < 4; ++i)
            #pragma unroll
            for (int j = 0; j < 4; ++j) {
                G[(ti + i) * BB + tj + j] = acc[i][j];
                sm->Gs[ti + i][tj + j] = acc[i][j];
            }
        __syncthreads();
        const int s = tid & 63, w = tid >> 6;
        for (int rr = 0; rr < 16; ++rr) {
            int row = w * 16 + rr;
            float x = (s < row) ? sm->Gs[row][s] : 0.f;
            #pragma unroll
            for (int o = 1; o < 64; o <<= 1) {
                float y = __shfl_down(x, o);
                if (s + o < 64) x += y;
            }
            Pfx[row * BB + s] = x;
        }
        return;
    }

    // ---------- k1_s0 tile ----------
    K1Smem* sm = (K1Smem*)blob;
    const int b = blockIdx.x - 1;
    const int lane = tid & 63, w = tid >> 6;
    const int jb = (b & 127) * 64;
    const int by = b >> 7;
    const int dbase = by * 256;
    const int t4 = ((w << 2) | (lane >> 4)) << 2;
    const int jq0 = lane & 15;
    float acc[4][4];
    #pragma unroll
    for (int i = 0; i < 4; ++i)
        #pragma unroll
        for (int q = 0; q < 4; ++q) acc[i][q] = 0.f;
    float sqa = 0.f;
    for (int dt = 0; dt < 4; ++dt) {
        int d0 = dbase + dt * 64;
        #pragma unroll
        for (int i = 0; i < 16; ++i) {
            int e = i * 256 + tid; int r = e >> 6, c = e & 63;
            sm->Ks[r * 65 + c] = K[r * DD + d0 + c];
            float m = MK0[(d0 + r) * MM + jb + c];
            sm->Ms[r * 65 + c] = m;
            sqa += m * m;
        }
        __syncthreads();
        #pragma unroll 4
        for (int dl = 0; dl < 64; ++dl) {
            float kv[4], mv[4];
            #pragma unroll
            for (int i = 0; i < 4; ++i) kv[i] = sm->Ks[(t4 + i) * 65 + dl];
            #pragma unroll
            for (int q = 0; q < 4; ++q) mv[q] = sm->Ms[dl * 65 + jq0 + 16 * q];
            #pragma unroll
            for (int i = 0; i < 4; ++i)
                #pragma unroll
                for (int q = 0; q < 4; ++q) acc[i][q] += kv[i] * mv[q];
        }
        __syncthreads();
    }
    #pragma unroll
    for (int i = 0; i < 4; ++i)
        #pragma unroll
        for (int q = 0; q < 4; ++q)
            S0p[by * BB * MM + (t4 + i) * MM + jb + jq0 + 16 * q] = acc[i][q];
    sm->sq[w * 64 + lane] = sqa;
    __syncthreads();
    if (w == 0) n2p[by * MM + jb + lane] =
        sm->sq[lane] + sm->sq[64 + lane] + sm->sq[128 + lane] + sm->sq[192 + lane];
}

// ---------------- K1b: cold E matrix + Spart row-sum partials (ks folded in) ----------------
__global__ __launch_bounds__(64) void k1b_ecold(const float* __restrict__ S0p,
                                                const float* __restrict__ G,
                                                const float* __restrict__ Pfx,
                                                const float* __restrict__ n2p,
                                                const float* __restrict__ bp,
                                                float* __restrict__ Ecold,
                                                float* __restrict__ Spart) {
    __shared__ float Pfx0s[BB], invks[BB], k2s[BB];
    int tid = threadIdx.x;             // 0..63
    const int b = blockIdx.x;          // 0..127
    int j = b * 64 + tid;
    {
        float g = G[tid * BB + tid];
        k2s[tid] = g;
        invks[tid] = __builtin_amdgcn_rsqf(g);
        Pfx0s[tid] = Pfx[tid * BB + 0];
    }
    const float beta = 1.f / (1.f + expf(-bp[0]));
    const float cuni = beta / (float)MM;
    float n2c = n2p[j] + n2p[MM + j];
    __syncthreads();
    float pa = S0p[j];
    float pb = S0p[BB * MM + j];
    for (int t = 0; t < BB; ++t) {
        float na = 0.f, nb = 0.f;
        if (t + 1 < BB) {
            na = S0p[(t + 1) * MM + j];
            nb = S0p[(BB + t + 1) * MM + j];
        }
        float s0 = pa + pb;
        float d_ = s0 + cuni * Pfx0s[t];
        float cosv = d_ * invks[t] * __builtin_amdgcn_rsqf(n2c);
        float ee = __expf(cosv);
        Ecold[t * MM + j] = ee;
        float rs = wave_sum64(ee);                 // deterministic tree
        if (tid == 0) Spart[t * 128 + b] = rs;
        n2c = n2c + 2.f * cuni * d_ + cuni * cuni * k2s[t];
        pa = na; pb = nb;
    }
}

// ---------------- K23: block 0 = scan; blocks 1..128 = DOUBLE k3 tiles ----------------
// R11: amdgpu_waves_per_eu(2,2) pins 2 waves/SIMD (what the grid gives anyway at 1 block/CU)
// -> VGPR budget 256/wave. Without it hipcc targeted 8 waves/SIMD (64-VGPR budget) and
// SPILLED the 64-float register arrays (wu + 3 row buffers) to scratch -- VGPR_Count=68
// proved it. Every "register prefetch" since R1 was actually scratch traffic (~L2 latency
// x 32+ accesses/step), which is why the step time was invariant to all scheduling changes.
// No arithmetic change -> bit-identical trajectory.
struct ScanSmem {
    u64   red[2][8];
    float EtabL[BB * BB];
    float EcTabL[BB * BB];
    float invSL[BB];
    float SL[BB];
    int   endL[BB];
    float invS_bc[2];
};
struct K3Smem2 {
    float Ws[64 * 65];
    float MsubA[64 * 65];
    float MsubB[64 * 65];
};
#define SMEM_BYTES ((sizeof(ScanSmem) > sizeof(K3Smem2)) ? sizeof(ScanSmem) : sizeof(K3Smem2))

__global__ __launch_bounds__(512)
__attribute__((amdgpu_waves_per_eu(2, 2)))
void k23_scan_u1(const float* __restrict__ Ecold,
                 const float* __restrict__ G,
                 const float* __restrict__ Pfx,
                 const float* __restrict__ Spart,
                 const float* __restrict__ bp,
                 const float* __restrict__ gp,
                 const float* __restrict__ MK0,
                 float* __restrict__ Etab_g,
                 float* __restrict__ EcTab_g,
                 float* __restrict__ Sg,
                 float* __restrict__ invSg,
                 int*   __restrict__ endTab_g,
                 int*   __restrict__ hcolg,
                 float* __restrict__ parts) {
    __shared__ __align__(16) char smem_raw[SMEM_BYTES];
    const int tid = threadIdx.x;

    if (blockIdx.x != 0) {
        // ---------- double k3 tile (writes parts, exits) ----------
        K3Smem2* sm = (K3Smem2*)smem_raw;
        const int p = blockIdx.x - 1;      // 0..127
        const int by = p >> 2;             // 0..31
        const int half = tid >> 8;         // 0: waves 0-3, 1: waves 4-7
        const int g = tid & 255;
        const int d0 = (p & 3) * 128 + half * 64;
        const int lane = g & 63, w = g >> 6;
        const int t4 = ((w << 2) | (lane >> 4)) << 2;
        const int dq0 = lane & 15;
        float* Msub = half ? sm->MsubB : sm->MsubA;
        float acc[4][4];
        #pragma unroll
        for (int i = 0; i < 4; ++i)
            #pragma unroll
            for (int q = 0; q < 4; ++q) acc[i][q] = 0.f;
        for (int sub = 0; sub < 4; ++sub) {
            int jb = by * 256 + sub * 64;
            if (half == 0) {
                #pragma unroll
                for (int i = 0; i < 16; ++i) {
                    int e = i * 256 + g; int r = e >> 6, c = e & 63;
                    sm->Ws[r * 65 + c] = Ecold[r * MM + jb + c];
                    sm->MsubA[r * 65 + c] = MK0[(d0 + r) * MM + jb + c];
                }
            } else {
                #pragma unroll
                for (int i = 0; i < 16; ++i) {
                    int e = i * 256 + g; int r = e >> 6, c = e & 63;
                    sm->MsubB[r * 65 + c] = MK0[(d0 + r) * MM + jb + c];
                }
            }
            __syncthreads();
            #pragma unroll 4
            for (int jl = 0; jl < 64; ++jl) {
                float wv[4], mv[4];
                #pragma unroll
                for (int i = 0; i < 4; ++i) wv[i] = sm->Ws[(t4 + i) * 65 + jl];
                #pragma unroll
                for (int q = 0; q < 4; ++q) mv[q] = Msub[(dq0 + 16 * q) * 65 + jl];
                #pragma unroll
                for (int i = 0; i < 4; ++i)
                    #pragma unroll
                    for (int q = 0; q < 4; ++q) acc[i][q] += wv[i] * mv[q];
            }
            __syncthreads();
        }
        #pragma unroll
        for (int i = 0; i < 4; ++i)
            #pragma unroll
            for (int q = 0; q < 4; ++q)
                parts[(by * 64 + t4 + i) * DD + d0 + dq0 + 16 * q] = acc[i][q];
        return;
    }

    // ---------- block 0: the scan (R6 structure; Scold from Spart prologue) ----------
    ScanSmem* sm = (ScanSmem*)smem_raw;
    const int lane = tid & 63;
    const int wid = tid >> 6;
    const bool w0 = (wid == 0);

    const float beta  = 1.f / (1.f + expf(-bp[0]));
    const float gamma = gp[0];
    const float cuni  = beta / (float)MM;
    const float omb   = 1.f - beta;

    if (tid < BB) sm->endL[tid] = BB;

    const float4* Ec4 = reinterpret_cast<const float4*>(Ecold);

    float wu[K2C], e0[K2C], e1[K2C], e2[K2C];
    #pragma unroll
    for (int c = 0; c < K2C; ++c) wu[c] = 0.f;
    #pragma unroll
    for (int i = 0; i < K2C / 4; ++i) {
        float4 v = Ec4[i * K2T + tid];                  // row 0
        e0[4 * i + 0] = v.x; e0[4 * i + 1] = v.y; e0[4 * i + 2] = v.z; e0[4 * i + 3] = v.w;
        float4 u = Ec4[(MM / 4) + i * K2T + tid];       // row 1
        e1[4 * i + 0] = u.x; e1[4 * i + 1] = u.y; e1[4 * i + 2] = u.z; e1[4 * i + 3] = u.w;
    }

    // prologue: Scold[lane] = fixed-order sum over 128 block partials (R7/R8-verified)
    float scold_r = 0.f;
    if (w0) {
        const float4* sp4 = reinterpret_cast<const float4*>(Spart + lane * 128);
        float sc = 0.f;
        #pragma unroll 8
        for (int i = 0; i < 32; ++i) {
            float4 v = sp4[i];
            sc += v.x; sc += v.y; sc += v.z; sc += v.w;
        }
        scold_r = sc;
    }

    // slot state: WAVE 0 ONLY
    float slot_n2 = 0.f, slot_ec = 0.f, wu_hot = 0.f, e_true_c = 0.f;
    int   slot_j = -1;
    bool  slot_act = false;
    float k2_cur = 0.f, S_reg = 0.f, invS_reg = 0.f;

    if (w0) {
        float g0 = G[lane];
        k2_cur = readlane_f(g0, 0);      // G[0][0]
        S_reg = readlane_f(scold_r, 0);  // S(0): no active slots
        invS_reg = __builtin_amdgcn_rcpf(S_reg);
        if (lane == 0) sm->invS_bc[0] = invS_reg;
    }
    __syncthreads();

    auto step = [&](int t, float (&cur)[K2C], float (&ld)[K2C]) {
        // ---- phase 0: wave0 early gathers (OLDEST vmem) ----
        float grow_n = 0.f, pfx_n = 0.f, Ssc_n = 0.f, ecpf0 = 0.f;
        if (w0 && t + 1 < BB) {
            if (slot_act) ecpf0 = Ecold[(t + 1) * MM + slot_j];
            grow_n = G[(t + 1) * BB + lane];
            pfx_n  = Pfx[(t + 1) * BB + lane];
            Ssc_n  = readlane_f(scold_r, t + 1);
        }

        // ---- phase 1: combine 8 wave-partial argmins ----
        int j0; float minval;
        if (t == 0) { j0 = 0; minval = 0.f; }
        else {
            u64 pm = sm->red[t & 1][lane & 7];
            pm = wave_min8(pm);
            j0 = (int)(pm & 0xFFFFFFFFu);
            minval = __uint_as_float((unsigned)(pm >> 32));
        }
        const float cuni_t = (t == 0) ? 0.f : cuni;
        float invS = w0 ? invS_reg : sm->invS_bc[t & 1];

        float latev = 0.f, ecpf_t = 0.f;
        if (w0 && lane == t) {
            latev = Ecold[t * MM + j0];
            if (t + 1 < BB) ecpf_t = Ecold[(t + 1) * MM + j0];
        }
        __builtin_amdgcn_sched_barrier(0);
        if (t + 2 < BB) {
            #pragma unroll
            for (int i = 0; i < K2C / 4; ++i) {
                float4 v = Ec4[(t + 2) * (MM / 4) + i * K2T + tid];
                ld[4 * i + 0] = v.x; ld[4 * i + 1] = v.y; ld[4 * i + 2] = v.z; ld[4 * i + 3] = v.w;
            }
        }
        __builtin_amdgcn_sched_barrier(0);

        // ---- wave0: bookkeeping for t, lookahead for t+1 ----
        bool fresh = false;
        if (w0) {
            u64 sup = __ballot(slot_act && (slot_j == j0));
            const bool has_sup = (sup != 0ull);
            const int  ssup = has_sup ? (int)__builtin_ctzll(sup) : 0;

            if (slot_act) {
                float ww = cuni + ((t >= 2 && lane == t - 1) ? omb : 0.f);
                wu_hot = fmaf(gamma, wu_hot, fmaf(e_true_c, invS, ww));
            }
            float trans_wu = readlane_f(wu_hot, ssup);
            float trans_E  = readlane_f(e_true_c, ssup);

            if (lane == t) {
                slot_j = j0;
                float ww0 = cuni + ((t >= 1) ? omb : 0.f);
                slot_n2 = ww0 * ww0 * k2_cur;
                slot_act = true;
                if (has_sup) wu_hot = trans_wu;
                fresh = !has_sup;
            }
            if (has_sup) {
                if (lane == ssup) slot_act = false;
                if (lane == t) sm->endL[ssup] = t;
            }

            float etl = e_true_c, ecl = slot_ec;
            if (lane == t) { ecl = latev; etl = has_sup ? trans_E : latev; }
            sm->EtabL[t * BB + lane]  = etl;
            sm->EcTabL[t * BB + lane] = ecl;
            if (lane == 0) { sm->invSL[t] = invS; sm->SL[t] = S_reg; }

            if (fresh) wu_hot = fmaf(gamma, minval, fmaf(latev, invS, cuni_t));

            if (t + 1 < BB) {
                float d_ = cuni * pfx_n;
                if (lane >= 1) d_ += omb * grow_n;
                float k2n   = readlane_f(grow_n, t + 1);
                float invkn = __builtin_amdgcn_rsqf(k2n);
                float ecpf  = (lane == t) ? ecpf_t : ecpf0;
                float myDelta = 0.f;
                float e_n = 0.f;
                if (slot_act) {
                    e_n = __expf(d_ * invkn * __builtin_amdgcn_rsqf(slot_n2));
                    myDelta = e_n - ecpf;
                    slot_n2 = slot_n2 + 2.f * cuni * d_ + cuni * cuni * k2n;
                }
                float S_next = Ssc_n + wave_sum64(myDelta);
                float invS_next = __builtin_amdgcn_rcpf(S_next);
                if (lane == 0) sm->invS_bc[(t + 1) & 1] = invS_next;
                if (slot_act) slot_ec = ecpf;
                e_true_c = e_n;
                k2_cur = k2n;
                S_reg = S_next; invS_reg = invS_next;
            }
        }

        // ---- all waves: cold w_u fma + first-index min over 16 cols ----
        float vmin = 0.f; int jmin = 0;
        #pragma unroll
        for (int i = 0; i < 4; ++i) {
            #pragma unroll
            for (int q = 0; q < 4; ++q) {
                int c = i * 4 + q;
                float wun = fmaf(gamma, wu[c], fmaf(cur[c], invS, cuni_t));
                wu[c] = wun;
                int j = i * 2048 + (tid << 2) + q;
                if (c == 0) { vmin = wun; jmin = j; }
                else if (wun < vmin) { vmin = wun; jmin = j; }
            }
        }
        u64 key = (((u64)__float_as_uint(vmin)) << 32) | (unsigned)jmin;

        if (((j0 >> 2) & (K2T - 1)) == tid) {
            int cj = ((j0 >> 11) << 2) | (j0 & 3);
            #pragma unroll
            for (int c = 0; c < K2C; ++c) if (c == cj) wu[c] = __builtin_inff();
        }

        if (w0) {
            u64 skey = (slot_act && !fresh)
                     ? ((((u64)__float_as_uint(wu_hot)) << 32) | (unsigned)slot_j) : ~0ull;
            key = skey < key ? skey : key;
        }
        key = wave_min64_lane63(key);
        if (lane == 63) sm->red[(t + 1) & 1][wid] = key;

        asm volatile("s_waitcnt lgkmcnt(0)" ::: "memory");
        __builtin_amdgcn_s_barrier();
        asm volatile("" ::: "memory");
    };

    #pragma unroll 1
    for (int th = 0; th < 63; th += 3) {
        step(th + 0, e0, e2);
        step(th + 1, e1, e0);
        step(th + 2, e2, e1);
    }
    step(63, e0, e2);

    // epilogue: dump logs
    for (int i = tid; i < BB * BB; i += K2T) {
        Etab_g[i]  = sm->EtabL[i];
        EcTab_g[i] = sm->EcTabL[i];
    }
    if (tid < BB) {
        Sg[tid] = sm->SL[tid];
        invSg[tid] = sm->invSL[tid];
        endTab_g[tid] = sm->endL[tid];
    }
    if (w0) hcolg[lane] = slot_j;
}

// ---------------- K3b: gather hot columns of MK0 into MKhot[s][d] (coalesced staging, once) ----------------
__global__ __launch_bounds__(512) void k3b_gather(const float* __restrict__ MK0, const int* __restrict__ hcolg,
                                                  float* __restrict__ MKhot) {
    int i = blockIdx.x, d = threadIdx.x;
    int h = hcolg[i];
    MKhot[i * DD + d] = MK0[d * MM + h];
}

// ---------------- K4: rebuild A/Dcol rows + final combine (coalesced MKhot reads) ----------------
__global__ __launch_bounds__(512) void k4_final(const float* __restrict__ parts,
                                                const float* __restrict__ K,
                                                const float* __restrict__ Etab,
                                                const float* __restrict__ EcTab,
                                                const int*   __restrict__ endTab,
                                                const float* __restrict__ Sg,
                                                const float* __restrict__ invSg,
                                                const float* __restrict__ MKhot,
                                                const float* __restrict__ bp,
                                                float* __restrict__ out) {
    __shared__ float Arow[BB];
    __shared__ float Drow[BB];
    int t = blockIdx.x, d = threadIdx.x;
    if (d < BB) {
        const float beta = 1.f / (1.f + expf(-bp[0]));
        const float cuni = beta / (float)MM;
        const float omb  = 1.f - beta;
        int s = d;
        float Ev = Etab[t * BB + s];
        int endv = endTab[s];
        bool act = (s <= t) && (t < endv);
        float S = Sg[t], invS = invSg[t];
        float ev = act ? Ev : 0.f;
        float x = ev;
        #pragma unroll
        for (int o = 1; o < 64; o <<= 1) {
            float y = __shfl_down(x, o);
            if (s + o < 64) x += y;
        }
        float suf = x - ev;
        float arow = 0.f;
        if (s < t) {
            float Qe = S - suf;
            arow = cuni * Qe;
            if (s >= 1 && act) arow += omb * Ev;
            arow *= invS;
        }
        Arow[s] = arow;
        Drow[s] = act ? (-invS * EcTab[t * BB + s]) : 0.f;
    }
    __syncthreads();
    float isv = invSg[t];
    float s1 = 0.f;
    #pragma unroll
    for (int p = 0; p < 32; ++p) s1 += parts[(p * 64 + t) * DD + d];
    float s2 = 0.f;
    for (int i = 0; i < BB; ++i) s2 += Drow[i] * MKhot[i * DD + d];
    float s3 = 0.f;
    for (int i = 0; i < BB; ++i) s3 += Arow[i] * K[i * DD + d];
    out[t * DD + d] = isv * s1 + s2 + s3;
}

extern "C" void kernel_launch(void* const* d_in, const int* in_sizes, int n_in,
                              void* d_out, int out_size, void* d_ws, size_t ws_size,
                              hipStream_t stream) {
    const float* K   = (const float*)d_in[0];   // k: [B,1,D]
    // d_in[1] = u: unused
    const float* MK0 = (const float*)d_in[2];   // memory_knowledge: [D,M]
    // d_in[3] = memory_understanding: unused
    const float* bp  = (const float*)d_in[4];   // beta_param
    const float* gp  = (const float*)d_in[5];   // memory_gamma

    float* ws    = (float*)d_ws;
    float* G     = ws;                  // 4096
    float* Pfx   = G + 4096;            // 4096
    float* S0p   = Pfx + 4096;          // 2*64*8192 = 1048576
    float* n2p   = S0p + 1048576;       // 16384
    float* Ecold = n2p + 16384;         // 524288
    float* Spart = Ecold + 524288;      // 64*128 = 8192
    float* Etab  = Spart + 8192;        // 4096
    float* EcTab = Etab + 4096;         // 4096
    float* Sarr  = EcTab + 4096;        // 64
    float* invS  = Sarr + 64;           // 64
    float* MKhot = invS + 64;           // 32768
    float* parts = MKhot + 32768;       // 32*64*512 = 1048576
    int*   hcol  = (int*)(parts + 1048576);  // 64
    int*   endT  = hcol + 64;                // 64
    float* out   = (float*)d_out;       // [B,1,D] f32

    ka_gram_s0  <<<257, 256, 0, stream>>>(K, MK0, G, Pfx, S0p, n2p);
    k1b_ecold   <<<128, 64, 0, stream>>>(S0p, G, Pfx, n2p, bp, Ecold, Spart);
    k23_scan_u1 <<<129, 512, 0, stream>>>(Ecold, G, Pfx, Spart, bp, gp, MK0,
                                          Etab, EcTab, Sarr, invS, endT, hcol, parts);
    k3b_gather  <<<64, 512, 0, stream>>>(MK0, hcol, MKhot);
    k4_final    <<<64, 512, 0, stream>>>(parts, K, Etab, EcTab, endT, Sarr, invS, MKhot, bp, out);
}

// Round 12
// 214.561 us; speedup vs baseline: 1.0585x; 1.0585x over previous
//
#include <hip/hip_runtime.h>
#include <math.h>

#define BB 64
#define DD 512
#define MM 8192
#define K2T 512   // scan threads (8 waves)
#define K2C 16    // MM / K2T cold columns per thread (4 float4)

typedef unsigned long long u64;

// ---------------- DPP wave-64 primitives ----------------
template<int CTRL>
__device__ __forceinline__ float dpp_addf(float x) {
    int y = __builtin_amdgcn_update_dpp(0, __float_as_int(x), CTRL, 0xF, 0xF, true);
    return x + __int_as_float(y);
}
__device__ __forceinline__ float wave_sum64(float x) {
    x = dpp_addf<0x111>(x); x = dpp_addf<0x112>(x); x = dpp_addf<0x114>(x); x = dpp_addf<0x118>(x);
    x = dpp_addf<0x142>(x); x = dpp_addf<0x143>(x);
    return __int_as_float(__builtin_amdgcn_readlane(__float_as_int(x), 63));
}
__device__ __forceinline__ float readlane_f(float v, int l) {
    return __int_as_float(__builtin_amdgcn_readlane(__float_as_int(v), l));
}
template<int CTRL>
__device__ __forceinline__ u64 dpp_min_step(u64 k) {
    unsigned lo = (unsigned)k, hi = (unsigned)(k >> 32);
    unsigned nlo = (unsigned)__builtin_amdgcn_update_dpp((int)0xFFFFFFFFu, (int)lo, CTRL, 0xF, 0xF, false);
    unsigned nhi = (unsigned)__builtin_amdgcn_update_dpp((int)0xFFFFFFFFu, (int)hi, CTRL, 0xF, 0xF, false);
    u64 nk = (((u64)nhi) << 32) | (u64)nlo;
    return nk < k ? nk : k;
}
__device__ __forceinline__ u64 wave_min64_lane63(u64 k) {
    k = dpp_min_step<0x111>(k); k = dpp_min_step<0x112>(k); k = dpp_min_step<0x114>(k);
    k = dpp_min_step<0x118>(k); k = dpp_min_step<0x142>(k); k = dpp_min_step<0x143>(k);
    return k;
}
__device__ __forceinline__ u64 wave_min8(u64 k) {
    k = dpp_min_step<0x111>(k); k = dpp_min_step<0x112>(k); k = dpp_min_step<0x114>(k);
    unsigned lo = (unsigned)__builtin_amdgcn_readlane((int)(unsigned)k, 7);
    unsigned hi = (unsigned)__builtin_amdgcn_readlane((int)(unsigned)(k >> 32), 7);
    return (((u64)hi) << 32) | (u64)lo;
}

// ---------------- flag helpers (agent scope; verified in R7) ----------------
__device__ __forceinline__ void flag_release(int* p, int v) {
    __threadfence();
    __hip_atomic_store(p, v, __ATOMIC_RELEASE, __HIP_MEMORY_SCOPE_AGENT);
}
__device__ __forceinline__ void spin_until_eq(int* p, int want) {
    while (__hip_atomic_load(p, __ATOMIC_ACQUIRE, __HIP_MEMORY_SCOPE_AGENT) != want)
        __builtin_amdgcn_s_sleep(2);
}

// ================ KAB: block 0 = Gram (G, Pfx) + flag; blocks 1..128 = full-depth
// K@MK0 (both halves) -> spin on gram flag (GEMM overlaps the gram; spin ~0-3 us) ->
// k1b recurrence -> Ecold + Spart partials. R7-verified bit-identical. ================
struct K0Smem {
    float Ks[BB][129];
    float Gs[BB][BB];
};
struct KbSmem {
    float Ks[64 * 65];
    float Ms[64 * 65];
    float S0s[64 * 65];
    float sq[4 * 64];
    float n2A[64];
    float n2full[64];
    float Pfx0s[BB], invks[BB], k2s[BB];
};
#define KAB_SMEM ((sizeof(K0Smem) > sizeof(KbSmem)) ? sizeof(K0Smem) : sizeof(KbSmem))

__global__ __launch_bounds__(256) void kab_gram_ecold(const float* __restrict__ K,
                                                      const float* __restrict__ MK0,
                                                      const float* __restrict__ bp,
                                                      float* __restrict__ G, float* __restrict__ Pfx,
                                                      float* __restrict__ Ecold,
                                                      float* __restrict__ Spart,
                                                      int* __restrict__ flags) {
    __shared__ __align__(16) char blob[KAB_SMEM];
    const int tid = threadIdx.x;

    if (blockIdx.x == 0) {
        // ---------- Gram + prefix (verbatim) ----------
        K0Smem* sm = (K0Smem*)blob;
        const int ti = ((tid >> 4) & 15) << 2;
        const int tj = (tid & 15) << 2;
        float acc[4][4];
        #pragma unroll
        for (int i = 0; i < 4; ++i)
            #pragma unroll
            for (int j = 0; j < 4; ++j) acc[i][j] = 0.f;
        for (int d0 = 0; d0 < DD; d0 += 128) {
            #pragma unroll
            for (int i = 0; i < 32; ++i) {
                int e = i * 256 + tid; int r = e >> 7, c = e & 127;
                sm->Ks[r][c] = K[r * DD + d0 + c];
            }
            __syncthreads();
            for (int dl = 0; dl < 128; ++dl) {
                float rv[4], cv[4];
                #pragma unroll
                for (int i = 0; i < 4; ++i) rv[i] = sm->Ks[ti + i][dl];
                #pragma unroll
                for (int j = 0; j < 4; ++j) cv[j] = sm->Ks[tj + j][dl];
                #pragma unroll
                for (int i = 0; i < 4; ++i)
                    #pragma unroll
                    for (int j = 0; j < 4; ++j) acc[i][j] += rv[i] * cv[j];
            }
            __syncthreads();
        }
        #pragma unroll
        for (int i = 0; i < 4; ++i)
            #pragma unroll
            for (int j = 0; j < 4; ++j) {
                G[(ti + i) * BB + tj + j] = acc[i][j];
                sm->Gs[ti + i][tj + j] = acc[i][j];
            }
        __syncthreads();
        const int s = tid & 63, w = tid >> 6;
        for (int rr = 0; rr < 16; ++rr) {
            int row = w * 16 + rr;
            float x = (s < row) ? sm->Gs[row][s] : 0.f;
            #pragma unroll
            for (int o = 1; o < 64; o <<= 1) {
                float y = __shfl_down(x, o);
                if (s + o < 64) x += y;
            }
            Pfx[row * BB + s] = x;
        }
        __syncthreads();
        if (tid == 0) flag_release(&flags[0], 1);   // G + Pfx published
        return;
    }

    // ---------- blocks 1..128: full-depth GEMM, then recurrence ----------
    KbSmem* sm = (KbSmem*)blob;
    const int b = blockIdx.x - 1;          // 0..127
    const int lane = tid & 63, w = tid >> 6;
    const int jb = b * 64;
    const int t4 = ((w << 2) | (lane >> 4)) << 2;
    const int jq0 = lane & 15;

    float accA[4][4], accB[4][4];
    #pragma unroll
    for (int i = 0; i < 4; ++i)
        #pragma unroll
        for (int q = 0; q < 4; ++q) { accA[i][q] = 0.f; accB[i][q] = 0.f; }
    float sqaA = 0.f, sqaB = 0.f;
    // half A: d 0..255
    for (int dt = 0; dt < 4; ++dt) {
        int d0 = dt * 64;
        #pragma unroll
        for (int i = 0; i < 16; ++i) {
            int e = i * 256 + tid; int r = e >> 6, c = e & 63;
            sm->Ks[r * 65 + c] = K[r * DD + d0 + c];
            float m = MK0[(d0 + r) * MM + jb + c];
            sm->Ms[r * 65 + c] = m;
            sqaA += m * m;
        }
        __syncthreads();
        #pragma unroll 4
        for (int dl = 0; dl < 64; ++dl) {
            float kv[4], mv[4];
            #pragma unroll
            for (int i = 0; i < 4; ++i) kv[i] = sm->Ks[(t4 + i) * 65 + dl];
            #pragma unroll
            for (int q = 0; q < 4; ++q) mv[q] = sm->Ms[dl * 65 + jq0 + 16 * q];
            #pragma unroll
            for (int i = 0; i < 4; ++i)
                #pragma unroll
                for (int q = 0; q < 4; ++q) accA[i][q] += kv[i] * mv[q];
        }
        __syncthreads();
    }
    // half B: d 256..511
    for (int dt = 0; dt < 4; ++dt) {
        int d0 = 256 + dt * 64;
        #pragma unroll
        for (int i = 0; i < 16; ++i) {
            int e = i * 256 + tid; int r = e >> 6, c = e & 63;
            sm->Ks[r * 65 + c] = K[r * DD + d0 + c];
            float m = MK0[(d0 + r) * MM + jb + c];
            sm->Ms[r * 65 + c] = m;
            sqaB += m * m;
        }
        __syncthreads();
        #pragma unroll 4
        for (int dl = 0; dl < 64; ++dl) {
            float kv[4], mv[4];
            #pragma unroll
            for (int i = 0; i < 4; ++i) kv[i] = sm->Ks[(t4 + i) * 65 + dl];
            #pragma unroll
            for (int q = 0; q < 4; ++q) mv[q] = sm->Ms[dl * 65 + jq0 + 16 * q];
            #pragma unroll
            for (int i = 0; i < 4; ++i)
                #pragma unroll
                for (int q = 0; q < 4; ++q) accB[i][q] += kv[i] * mv[q];
        }
        __syncthreads();
    }
    // n2 (per-half reductions then A+B)
    sm->sq[w * 64 + lane] = sqaA;
    __syncthreads();
    if (w == 0) sm->n2A[lane] = sm->sq[lane] + sm->sq[64 + lane] + sm->sq[128 + lane] + sm->sq[192 + lane];
    __syncthreads();
    sm->sq[w * 64 + lane] = sqaB;
    __syncthreads();
    if (w == 0) {
        float b4 = sm->sq[lane] + sm->sq[64 + lane] + sm->sq[128 + lane] + sm->sq[192 + lane];
        sm->n2full[lane] = sm->n2A[lane] + b4;
    }
    // S0 into LDS
    #pragma unroll
    for (int i = 0; i < 4; ++i)
        #pragma unroll
        for (int q = 0; q < 4; ++q)
            sm->S0s[(t4 + i) * 65 + jq0 + 16 * q] = accA[i][q] + accB[i][q];
    // wait for gram (overlapped with the GEMM above)
    if (tid == 0) spin_until_eq(&flags[0], 1);
    __syncthreads();
    if (tid < BB) {
        float g = G[tid * BB + tid];
        sm->k2s[tid] = g;
        sm->invks[tid] = __builtin_amdgcn_rsqf(g);
        sm->Pfx0s[tid] = Pfx[tid * BB + 0];
    }
    __syncthreads();
    // recurrence (verbatim k1b) + per-t block row-sum partial
    if (w == 0) {
        const float beta = 1.f / (1.f + expf(-bp[0]));
        const float cuni = beta / (float)MM;
        int j = jb + lane;
        float n2c = sm->n2full[lane];
        for (int t = 0; t < BB; ++t) {
            float s0 = sm->S0s[t * 65 + lane];
            float d_ = s0 + cuni * sm->Pfx0s[t];
            float cosv = d_ * sm->invks[t] * __builtin_amdgcn_rsqf(n2c);
            float ee = __expf(cosv);
            Ecold[t * MM + j] = ee;
            float rs = wave_sum64(ee);
            if (lane == 0) Spart[t * 128 + b] = rs;
            n2c = n2c + 2.f * cuni * d_ + cuni * cuni * sm->k2s[t];
        }
    }
}

// ---------------- K23: block 0 = scan; blocks 1..128 = DOUBLE k3 tiles (R10 exact) ----------------
struct ScanSmem {
    u64   red[2][8];
    float EtabL[BB * BB];
    float EcTabL[BB * BB];
    float invSL[BB];
    float SL[BB];
    int   endL[BB];
    float invS_bc[2];
};
struct K3Smem2 {
    float Ws[64 * 65];
    float MsubA[64 * 65];
    float MsubB[64 * 65];
};
#define SMEM_BYTES ((sizeof(ScanSmem) > sizeof(K3Smem2)) ? sizeof(ScanSmem) : sizeof(K3Smem2))

__global__ __launch_bounds__(512) void k23_scan_u1(const float* __restrict__ Ecold,
                                                   const float* __restrict__ G,
                                                   const float* __restrict__ Pfx,
                                                   const float* __restrict__ Spart,
                                                   const float* __restrict__ bp,
                                                   const float* __restrict__ gp,
                                                   const float* __restrict__ MK0,
                                                   float* __restrict__ Etab_g,
                                                   float* __restrict__ EcTab_g,
                                                   float* __restrict__ Sg,
                                                   float* __restrict__ invSg,
                                                   int*   __restrict__ endTab_g,
                                                   int*   __restrict__ hcolg,
                                                   float* __restrict__ parts) {
    __shared__ __align__(16) char smem_raw[SMEM_BYTES];
    const int tid = threadIdx.x;

    if (blockIdx.x != 0) {
        // ---------- double k3 tile (writes parts, exits) ----------
        K3Smem2* sm = (K3Smem2*)smem_raw;
        const int p = blockIdx.x - 1;      // 0..127
        const int by = p >> 2;             // 0..31
        const int half = tid >> 8;         // 0: waves 0-3, 1: waves 4-7
        const int g = tid & 255;
        const int d0 = (p & 3) * 128 + half * 64;
        const int lane = g & 63, w = g >> 6;
        const int t4 = ((w << 2) | (lane >> 4)) << 2;
        const int dq0 = lane & 15;
        float* Msub = half ? sm->MsubB : sm->MsubA;
        float acc[4][4];
        #pragma unroll
        for (int i = 0; i < 4; ++i)
            #pragma unroll
            for (int q = 0; q < 4; ++q) acc[i][q] = 0.f;
        for (int sub = 0; sub < 4; ++sub) {
            int jb = by * 256 + sub * 64;
            if (half == 0) {
                #pragma unroll
                for (int i = 0; i < 16; ++i) {
                    int e = i * 256 + g; int r = e >> 6, c = e & 63;
                    sm->Ws[r * 65 + c] = Ecold[r * MM + jb + c];
                    sm->MsubA[r * 65 + c] = MK0[(d0 + r) * MM + jb + c];
                }
            } else {
                #pragma unroll
                for (int i = 0; i < 16; ++i) {
                    int e = i * 256 + g; int r = e >> 6, c = e & 63;
                    sm->MsubB[r * 65 + c] = MK0[(d0 + r) * MM + jb + c];
                }
            }
            __syncthreads();
            #pragma unroll 4
            for (int jl = 0; jl < 64; ++jl) {
                float wv[4], mv[4];
                #pragma unroll
                for (int i = 0; i < 4; ++i) wv[i] = sm->Ws[(t4 + i) * 65 + jl];
                #pragma unroll
                for (int q = 0; q < 4; ++q) mv[q] = Msub[(dq0 + 16 * q) * 65 + jl];
                #pragma unroll
                for (int i = 0; i < 4; ++i)
                    #pragma unroll
                    for (int q = 0; q < 4; ++q) acc[i][q] += wv[i] * mv[q];
            }
            __syncthreads();
        }
        #pragma unroll
        for (int i = 0; i < 4; ++i)
            #pragma unroll
            for (int q = 0; q < 4; ++q)
                parts[(by * 64 + t4 + i) * DD + d0 + dq0 + 16 * q] = acc[i][q];
        return;
    }

    // ---------- block 0: the scan (R6 structure; Scold from Spart prologue) ----------
    ScanSmem* sm = (ScanSmem*)smem_raw;
    const int lane = tid & 63;
    const int wid = tid >> 6;
    const bool w0 = (wid == 0);

    const float beta  = 1.f / (1.f + expf(-bp[0]));
    const float gamma = gp[0];
    const float cuni  = beta / (float)MM;
    const float omb   = 1.f - beta;

    if (tid < BB) sm->endL[tid] = BB;

    const float4* Ec4 = reinterpret_cast<const float4*>(Ecold);

    float wu[K2C], e0[K2C], e1[K2C], e2[K2C];
    #pragma unroll
    for (int c = 0; c < K2C; ++c) wu[c] = 0.f;
    #pragma unroll
    for (int i = 0; i < K2C / 4; ++i) {
        float4 v = Ec4[i * K2T + tid];                  // row 0
        e0[4 * i + 0] = v.x; e0[4 * i + 1] = v.y; e0[4 * i + 2] = v.z; e0[4 * i + 3] = v.w;
        float4 u = Ec4[(MM / 4) + i * K2T + tid];       // row 1
        e1[4 * i + 0] = u.x; e1[4 * i + 1] = u.y; e1[4 * i + 2] = u.z; e1[4 * i + 3] = u.w;
    }

    // prologue: Scold[lane] = fixed-order sum over 128 block partials (R7/R8-verified)
    float scold_r = 0.f;
    if (w0) {
        const float4* sp4 = reinterpret_cast<const float4*>(Spart + lane * 128);
        float sc = 0.f;
        #pragma unroll 8
        for (int i = 0; i < 32; ++i) {
            float4 v = sp4[i];
            sc += v.x; sc += v.y; sc += v.z; sc += v.w;
        }
        scold_r = sc;
    }

    // slot state: WAVE 0 ONLY
    float slot_n2 = 0.f, slot_ec = 0.f, wu_hot = 0.f, e_true_c = 0.f;
    int   slot_j = -1;
    bool  slot_act = false;
    float k2_cur = 0.f, S_reg = 0.f, invS_reg = 0.f;

    if (w0) {
        float g0 = G[lane];
        k2_cur = readlane_f(g0, 0);      // G[0][0]
        S_reg = readlane_f(scold_r, 0);  // S(0): no active slots
        invS_reg = __builtin_amdgcn_rcpf(S_reg);
        if (lane == 0) sm->invS_bc[0] = invS_reg;
    }
    __syncthreads();

    auto step = [&](int t, float (&cur)[K2C], float (&ld)[K2C]) {
        // ---- phase 0: wave0 early gathers (OLDEST vmem) ----
        float grow_n = 0.f, pfx_n = 0.f, Ssc_n = 0.f, ecpf0 = 0.f;
        if (w0 && t + 1 < BB) {
            if (slot_act) ecpf0 = Ecold[(t + 1) * MM + slot_j];
            grow_n = G[(t + 1) * BB + lane];
            pfx_n  = Pfx[(t + 1) * BB + lane];
            Ssc_n  = readlane_f(scold_r, t + 1);
        }

        // ---- phase 1: combine 8 wave-partial argmins ----
        int j0; float minval;
        if (t == 0) { j0 = 0; minval = 0.f; }
        else {
            u64 pm = sm->red[t & 1][lane & 7];
            pm = wave_min8(pm);
            j0 = (int)(pm & 0xFFFFFFFFu);
            minval = __uint_as_float((unsigned)(pm >> 32));
        }
        const float cuni_t = (t == 0) ? 0.f : cuni;
        float invS = w0 ? invS_reg : sm->invS_bc[t & 1];

        float latev = 0.f, ecpf_t = 0.f;
        if (w0 && lane == t) {
            latev = Ecold[t * MM + j0];
            if (t + 1 < BB) ecpf_t = Ecold[(t + 1) * MM + j0];
        }
        __builtin_amdgcn_sched_barrier(0);
        if (t + 2 < BB) {
            #pragma unroll
            for (int i = 0; i < K2C / 4; ++i) {
                float4 v = Ec4[(t + 2) * (MM / 4) + i * K2T + tid];
                ld[4 * i + 0] = v.x; ld[4 * i + 1] = v.y; ld[4 * i + 2] = v.z; ld[4 * i + 3] = v.w;
            }
        }
        __builtin_amdgcn_sched_barrier(0);

        // ---- wave0: bookkeeping for t, lookahead for t+1 ----
        bool fresh = false;
        if (w0) {
            u64 sup = __ballot(slot_act && (slot_j == j0));
            const bool has_sup = (sup != 0ull);
            const int  ssup = has_sup ? (int)__builtin_ctzll(sup) : 0;

            if (slot_act) {
                float ww = cuni + ((t >= 2 && lane == t - 1) ? omb : 0.f);
                wu_hot = fmaf(gamma, wu_hot, fmaf(e_true_c, invS, ww));
            }
            float trans_wu = readlane_f(wu_hot, ssup);
            float trans_E  = readlane_f(e_true_c, ssup);

            if (lane == t) {
                slot_j = j0;
                float ww0 = cuni + ((t >= 1) ? omb : 0.f);
                slot_n2 = ww0 * ww0 * k2_cur;
                slot_act = true;
                if (has_sup) wu_hot = trans_wu;
                fresh = !has_sup;
            }
            if (has_sup) {
                if (lane == ssup) slot_act = false;
                if (lane == t) sm->endL[ssup] = t;
            }

            float etl = e_true_c, ecl = slot_ec;
            if (lane == t) { ecl = latev; etl = has_sup ? trans_E : latev; }
            sm->EtabL[t * BB + lane]  = etl;
            sm->EcTabL[t * BB + lane] = ecl;
            if (lane == 0) { sm->invSL[t] = invS; sm->SL[t] = S_reg; }

            if (fresh) wu_hot = fmaf(gamma, minval, fmaf(latev, invS, cuni_t));

            if (t + 1 < BB) {
                float d_ = cuni * pfx_n;
                if (lane >= 1) d_ += omb * grow_n;
                float k2n   = readlane_f(grow_n, t + 1);
                float invkn = __builtin_amdgcn_rsqf(k2n);
                float ecpf  = (lane == t) ? ecpf_t : ecpf0;
                float myDelta = 0.f;
                float e_n = 0.f;
                if (slot_act) {
                    e_n = __expf(d_ * invkn * __builtin_amdgcn_rsqf(slot_n2));
                    myDelta = e_n - ecpf;
                    slot_n2 = slot_n2 + 2.f * cuni * d_ + cuni * cuni * k2n;
                }
                float S_next = Ssc_n + wave_sum64(myDelta);
                float invS_next = __builtin_amdgcn_rcpf(S_next);
                if (lane == 0) sm->invS_bc[(t + 1) & 1] = invS_next;
                if (slot_act) slot_ec = ecpf;
                e_true_c = e_n;
                k2_cur = k2n;
                S_reg = S_next; invS_reg = invS_next;
            }
        }

        // ---- all waves: cold w_u fma + first-index min over 16 cols ----
        float vmin = 0.f; int jmin = 0;
        #pragma unroll
        for (int i = 0; i < 4; ++i) {
            #pragma unroll
            for (int q = 0; q < 4; ++q) {
                int c = i * 4 + q;
                float wun = fmaf(gamma, wu[c], fmaf(cur[c], invS, cuni_t));
                wu[c] = wun;
                int j = i * 2048 + (tid << 2) + q;
                if (c == 0) { vmin = wun; jmin = j; }
                else if (wun < vmin) { vmin = wun; jmin = j; }
            }
        }
        u64 key = (((u64)__float_as_uint(vmin)) << 32) | (unsigned)jmin;

        if (((j0 >> 2) & (K2T - 1)) == tid) {
            int cj = ((j0 >> 11) << 2) | (j0 & 3);
            #pragma unroll
            for (int c = 0; c < K2C; ++c) if (c == cj) wu[c] = __builtin_inff();
        }

        if (w0) {
            u64 skey = (slot_act && !fresh)
                     ? ((((u64)__float_as_uint(wu_hot)) << 32) | (unsigned)slot_j) : ~0ull;
            key = skey < key ? skey : key;
        }
        key = wave_min64_lane63(key);
        if (lane == 63) sm->red[(t + 1) & 1][wid] = key;

        asm volatile("s_waitcnt lgkmcnt(0)" ::: "memory");
        __builtin_amdgcn_s_barrier();
        asm volatile("" ::: "memory");
    };

    #pragma unroll 1
    for (int th = 0; th < 63; th += 3) {
        step(th + 0, e0, e2);
        step(th + 1, e1, e0);
        step(th + 2, e2, e1);
    }
    step(63, e0, e2);

    // epilogue: dump logs
    for (int i = tid; i < BB * BB; i += K2T) {
        Etab_g[i]  = sm->EtabL[i];
        EcTab_g[i] = sm->EcTabL[i];
    }
    if (tid < BB) {
        Sg[tid] = sm->SL[tid];
        invSg[tid] = sm->invSL[tid];
        endTab_g[tid] = sm->endL[tid];
    }
    if (w0) hcolg[lane] = slot_j;
}

// ---------------- K3b: gather hot columns of MK0 into MKhot[s][d] (coalesced staging, once) ----------------
__global__ __launch_bounds__(512) void k3b_gather(const float* __restrict__ MK0, const int* __restrict__ hcolg,
                                                  float* __restrict__ MKhot) {
    int i = blockIdx.x, d = threadIdx.x;
    int h = hcolg[i];
    MKhot[i * DD + d] = MK0[d * MM + h];
}

// ---------------- K4: rebuild A/Dcol rows + final combine (coalesced MKhot reads) ----------------
__global__ __launch_bounds__(512) void k4_final(const float* __restrict__ parts,
                                                const float* __restrict__ K,
                                                const float* __restrict__ Etab,
                                                const float* __restrict__ EcTab,
                                                const int*   __restrict__ endTab,
                                                const float* __restrict__ Sg,
                                                const float* __restrict__ invSg,
                                                const float* __restrict__ MKhot,
                                                const float* __restrict__ bp,
                                                float* __restrict__ out) {
    __shared__ float Arow[BB];
    __shared__ float Drow[BB];
    int t = blockIdx.x, d = threadIdx.x;
    if (d < BB) {
        const float beta = 1.f / (1.f + expf(-bp[0]));
        const float cuni = beta / (float)MM;
        const float omb  = 1.f - beta;
        int s = d;
        float Ev = Etab[t * BB + s];
        int endv = endTab[s];
        bool act = (s <= t) && (t < endv);
        float S = Sg[t], invS = invSg[t];
        float ev = act ? Ev : 0.f;
        float x = ev;
        #pragma unroll
        for (int o = 1; o < 64; o <<= 1) {
            float y = __shfl_down(x, o);
            if (s + o < 64) x += y;
        }
        float suf = x - ev;
        float arow = 0.f;
        if (s < t) {
            float Qe = S - suf;
            arow = cuni * Qe;
            if (s >= 1 && act) arow += omb * Ev;
            arow *= invS;
        }
        Arow[s] = arow;
        Drow[s] = act ? (-invS * EcTab[t * BB + s]) : 0.f;
    }
    __syncthreads();
    float isv = invSg[t];
    float s1 = 0.f;
    #pragma unroll
    for (int p = 0; p < 32; ++p) s1 += parts[(p * 64 + t) * DD + d];
    float s2 = 0.f;
    for (int i = 0; i < BB; ++i) s2 += Drow[i] * MKhot[i * DD + d];
    float s3 = 0.f;
    for (int i = 0; i < BB; ++i) s3 += Arow[i] * K[i * DD + d];
    out[t * DD + d] = isv * s1 + s2 + s3;
}

extern "C" void kernel_launch(void* const* d_in, const int* in_sizes, int n_in,
                              void* d_out, int out_size, void* d_ws, size_t ws_size,
                              hipStream_t stream) {
    const float* K   = (const float*)d_in[0];   // k: [B,1,D]
    // d_in[1] = u: unused
    const float* MK0 = (const float*)d_in[2];   // memory_knowledge: [D,M]
    // d_in[3] = memory_understanding: unused
    const float* bp  = (const float*)d_in[4];   // beta_param
    const float* gp  = (const float*)d_in[5];   // memory_gamma

    float* ws    = (float*)d_ws;
    float* G     = ws;                  // 4096
    float* Pfx   = G + 4096;            // 4096
    float* Ecold = Pfx + 4096;          // 524288
    float* Spart = Ecold + 524288;      // 64*128 = 8192
    float* Etab  = Spart + 8192;        // 4096
    float* EcTab = Etab + 4096;         // 4096
    float* Sarr  = EcTab + 4096;        // 64
    float* invS  = Sarr + 64;           // 64
    float* MKhot = invS + 64;           // 32768
    float* parts = MKhot + 32768;       // 32*64*512 = 1048576
    int*   hcol  = (int*)(parts + 1048576);  // 64
    int*   endT  = hcol + 64;                // 64
    int*   flags = endT + 64;                // [0] = gram done
    float* out   = (float*)d_out;       // [B,1,D] f32

    hipMemsetAsync(flags, 0, sizeof(int), stream);
    kab_gram_ecold <<<129, 256, 0, stream>>>(K, MK0, bp, G, Pfx, Ecold, Spart, flags);
    k23_scan_u1    <<<129, 512, 0, stream>>>(Ecold, G, Pfx, Spart, bp, gp, MK0,
                                             Etab, EcTab, Sarr, invS, endT, hcol, parts);
    k3b_gather     <<<64, 512, 0, stream>>>(MK0, hcol, MKhot);
    k4_final       <<<64, 512, 0, stream>>>(parts, K, Etab, EcTab, endT, Sarr, invS, MKhot, bp, out);
}

// Round 13
// 212.768 us; speedup vs baseline: 1.0674x; 1.0084x over previous
//
#include <hip/hip_runtime.h>
#include <math.h>

#define BB 64
#define DD 512
#define MM 8192
#define K2T 512   // scan threads (8 waves)
#define K2C 16    // MM / K2T cold columns per thread (4 float4)

typedef unsigned long long u64;

// ---------------- DPP wave-64 primitives ----------------
template<int CTRL>
__device__ __forceinline__ float dpp_addf(float x) {
    int y = __builtin_amdgcn_update_dpp(0, __float_as_int(x), CTRL, 0xF, 0xF, true);
    return x + __int_as_float(y);
}
__device__ __forceinline__ float wave_sum64(float x) {
    x = dpp_addf<0x111>(x); x = dpp_addf<0x112>(x); x = dpp_addf<0x114>(x); x = dpp_addf<0x118>(x);
    x = dpp_addf<0x142>(x); x = dpp_addf<0x143>(x);
    return __int_as_float(__builtin_amdgcn_readlane(__float_as_int(x), 63));
}
__device__ __forceinline__ float readlane_f(float v, int l) {
    return __int_as_float(__builtin_amdgcn_readlane(__float_as_int(v), l));
}
template<int CTRL>
__device__ __forceinline__ u64 dpp_min_step(u64 k) {
    unsigned lo = (unsigned)k, hi = (unsigned)(k >> 32);
    unsigned nlo = (unsigned)__builtin_amdgcn_update_dpp((int)0xFFFFFFFFu, (int)lo, CTRL, 0xF, 0xF, false);
    unsigned nhi = (unsigned)__builtin_amdgcn_update_dpp((int)0xFFFFFFFFu, (int)hi, CTRL, 0xF, 0xF, false);
    u64 nk = (((u64)nhi) << 32) | (u64)nlo;
    return nk < k ? nk : k;
}
__device__ __forceinline__ u64 wave_min64_lane63(u64 k) {
    k = dpp_min_step<0x111>(k); k = dpp_min_step<0x112>(k); k = dpp_min_step<0x114>(k);
    k = dpp_min_step<0x118>(k); k = dpp_min_step<0x142>(k); k = dpp_min_step<0x143>(k);
    return k;
}
__device__ __forceinline__ u64 wave_min8(u64 k) {
    k = dpp_min_step<0x111>(k); k = dpp_min_step<0x112>(k); k = dpp_min_step<0x114>(k);
    unsigned lo = (unsigned)__builtin_amdgcn_readlane((int)(unsigned)k, 7);
    unsigned hi = (unsigned)__builtin_amdgcn_readlane((int)(unsigned)(k >> 32), 7);
    return (((u64)hi) << 32) | (u64)lo;
}

// ---------------- flag helpers (agent scope; verified in R7) ----------------
__device__ __forceinline__ void flag_release(int* p, int v) {
    __threadfence();
    __hip_atomic_store(p, v, __ATOMIC_RELEASE, __HIP_MEMORY_SCOPE_AGENT);
}
__device__ __forceinline__ void spin_until_eq(int* p, int want) {
    while (__hip_atomic_load(p, __ATOMIC_ACQUIRE, __HIP_MEMORY_SCOPE_AGENT) != want)
        __builtin_amdgcn_s_sleep(2);
}

// ================ KAB: block 0 = Gram (G, Pfx) + flag; blocks 1..128 = full-depth
// K@MK0 (both halves) -> spin on gram flag -> k1b recurrence -> Ecold + Spart ================
struct K0Smem {
    float Ks[BB][129];
    float Gs[BB][BB];
};
struct KbSmem {
    float Ks[64 * 65];
    float Ms[64 * 65];
    float S0s[64 * 65];
    float sq[4 * 64];
    float n2A[64];
    float n2full[64];
    float Pfx0s[BB], invks[BB], k2s[BB];
};
#define KAB_SMEM ((sizeof(K0Smem) > sizeof(KbSmem)) ? sizeof(K0Smem) : sizeof(KbSmem))

__global__ __launch_bounds__(256) void kab_gram_ecold(const float* __restrict__ K,
                                                      const float* __restrict__ MK0,
                                                      const float* __restrict__ bp,
                                                      float* __restrict__ G, float* __restrict__ Pfx,
                                                      float* __restrict__ Ecold,
                                                      float* __restrict__ Spart,
                                                      int* __restrict__ flags) {
    __shared__ __align__(16) char blob[KAB_SMEM];
    const int tid = threadIdx.x;

    if (blockIdx.x == 0) {
        // ---------- Gram + prefix (verbatim) ----------
        K0Smem* sm = (K0Smem*)blob;
        const int ti = ((tid >> 4) & 15) << 2;
        const int tj = (tid & 15) << 2;
        float acc[4][4];
        #pragma unroll
        for (int i = 0; i < 4; ++i)
            #pragma unroll
            for (int j = 0; j < 4; ++j) acc[i][j] = 0.f;
        for (int d0 = 0; d0 < DD; d0 += 128) {
            #pragma unroll
            for (int i = 0; i < 32; ++i) {
                int e = i * 256 + tid; int r = e >> 7, c = e & 127;
                sm->Ks[r][c] = K[r * DD + d0 + c];
            }
            __syncthreads();
            for (int dl = 0; dl < 128; ++dl) {
                float rv[4], cv[4];
                #pragma unroll
                for (int i = 0; i < 4; ++i) rv[i] = sm->Ks[ti + i][dl];
                #pragma unroll
                for (int j = 0; j < 4; ++j) cv[j] = sm->Ks[tj + j][dl];
                #pragma unroll
                for (int i = 0; i < 4; ++i)
                    #pragma unroll
                    for (int j = 0; j < 4; ++j) acc[i][j] += rv[i] * cv[j];
            }
            __syncthreads();
        }
        #pragma unroll
        for (int i = 0; i < 4; ++i)
            #pragma unroll
            for (int j = 0; j < 4; ++j) {
                G[(ti + i) * BB + tj + j] = acc[i][j];
                sm->Gs[ti + i][tj + j] = acc[i][j];
            }
        __syncthreads();
        const int s = tid & 63, w = tid >> 6;
        for (int rr = 0; rr < 16; ++rr) {
            int row = w * 16 + rr;
            float x = (s < row) ? sm->Gs[row][s] : 0.f;
            #pragma unroll
            for (int o = 1; o < 64; o <<= 1) {
                float y = __shfl_down(x, o);
                if (s + o < 64) x += y;
            }
            Pfx[row * BB + s] = x;
        }
        __syncthreads();
        if (tid == 0) flag_release(&flags[0], 1);   // G + Pfx published
        return;
    }

    // ---------- blocks 1..128: full-depth GEMM, then recurrence ----------
    KbSmem* sm = (KbSmem*)blob;
    const int b = blockIdx.x - 1;          // 0..127
    const int lane = tid & 63, w = tid >> 6;
    const int jb = b * 64;
    const int t4 = ((w << 2) | (lane >> 4)) << 2;
    const int jq0 = lane & 15;

    float accA[4][4], accB[4][4];
    #pragma unroll
    for (int i = 0; i < 4; ++i)
        #pragma unroll
        for (int q = 0; q < 4; ++q) { accA[i][q] = 0.f; accB[i][q] = 0.f; }
    float sqaA = 0.f, sqaB = 0.f;
    // half A: d 0..255
    for (int dt = 0; dt < 4; ++dt) {
        int d0 = dt * 64;
        #pragma unroll
        for (int i = 0; i < 16; ++i) {
            int e = i * 256 + tid; int r = e >> 6, c = e & 63;
            sm->Ks[r * 65 + c] = K[r * DD + d0 + c];
            float m = MK0[(d0 + r) * MM + jb + c];
            sm->Ms[r * 65 + c] = m;
            sqaA += m * m;
        }
        __syncthreads();
        #pragma unroll 4
        for (int dl = 0; dl < 64; ++dl) {
            float kv[4], mv[4];
            #pragma unroll
            for (int i = 0; i < 4; ++i) kv[i] = sm->Ks[(t4 + i) * 65 + dl];
            #pragma unroll
            for (int q = 0; q < 4; ++q) mv[q] = sm->Ms[dl * 65 + jq0 + 16 * q];
            #pragma unroll
            for (int i = 0; i < 4; ++i)
                #pragma unroll
                for (int q = 0; q < 4; ++q) accA[i][q] += kv[i] * mv[q];
        }
        __syncthreads();
    }
    // half B: d 256..511
    for (int dt = 0; dt < 4; ++dt) {
        int d0 = 256 + dt * 64;
        #pragma unroll
        for (int i = 0; i < 16; ++i) {
            int e = i * 256 + tid; int r = e >> 6, c = e & 63;
            sm->Ks[r * 65 + c] = K[r * DD + d0 + c];
            float m = MK0[(d0 + r) * MM + jb + c];
            sm->Ms[r * 65 + c] = m;
            sqaB += m * m;
        }
        __syncthreads();
        #pragma unroll 4
        for (int dl = 0; dl < 64; ++dl) {
            float kv[4], mv[4];
            #pragma unroll
            for (int i = 0; i < 4; ++i) kv[i] = sm->Ks[(t4 + i) * 65 + dl];
            #pragma unroll
            for (int q = 0; q < 4; ++q) mv[q] = sm->Ms[dl * 65 + jq0 + 16 * q];
            #pragma unroll
            for (int i = 0; i < 4; ++i)
                #pragma unroll
                for (int q = 0; q < 4; ++q) accB[i][q] += kv[i] * mv[q];
        }
        __syncthreads();
    }
    // n2 (per-half reductions then A+B)
    sm->sq[w * 64 + lane] = sqaA;
    __syncthreads();
    if (w == 0) sm->n2A[lane] = sm->sq[lane] + sm->sq[64 + lane] + sm->sq[128 + lane] + sm->sq[192 + lane];
    __syncthreads();
    sm->sq[w * 64 + lane] = sqaB;
    __syncthreads();
    if (w == 0) {
        float b4 = sm->sq[lane] + sm->sq[64 + lane] + sm->sq[128 + lane] + sm->sq[192 + lane];
        sm->n2full[lane] = sm->n2A[lane] + b4;
    }
    // S0 into LDS
    #pragma unroll
    for (int i = 0; i < 4; ++i)
        #pragma unroll
        for (int q = 0; q < 4; ++q)
            sm->S0s[(t4 + i) * 65 + jq0 + 16 * q] = accA[i][q] + accB[i][q];
    // wait for gram (overlapped with the GEMM above)
    if (tid == 0) spin_until_eq(&flags[0], 1);
    __syncthreads();
    if (tid < BB) {
        float g = G[tid * BB + tid];
        sm->k2s[tid] = g;
        sm->invks[tid] = __builtin_amdgcn_rsqf(g);
        sm->Pfx0s[tid] = Pfx[tid * BB + 0];
    }
    __syncthreads();
    // recurrence (verbatim k1b) + per-t block row-sum partial
    if (w == 0) {
        const float beta = 1.f / (1.f + expf(-bp[0]));
        const float cuni = beta / (float)MM;
        int j = jb + lane;
        float n2c = sm->n2full[lane];
        for (int t = 0; t < BB; ++t) {
            float s0 = sm->S0s[t * 65 + lane];
            float d_ = s0 + cuni * sm->Pfx0s[t];
            float cosv = d_ * sm->invks[t] * __builtin_amdgcn_rsqf(n2c);
            float ee = __expf(cosv);
            Ecold[t * MM + j] = ee;
            float rs = wave_sum64(ee);
            if (lane == 0) Spart[t * 128 + b] = rs;
            n2c = n2c + 2.f * cuni * d_ + cuni * cuni * sm->k2s[t];
        }
    }
}

// ---------------- K23: block 0 = scan; blocks 1..128 = DOUBLE k3 tiles ----------------
// R13: the step body is a MACRO (textual expansion), not a lambda-with-array-refs.
// The lambda captured wu[]/e0..e2[] and all carried scalars BY REFERENCE -> address
// escape -> allocas in scratch -> every asm "memory" barrier clobber forced spill/
// reload of the whole state each step (VGPR_Count=68 proved arrays were NOT in regs;
// scratch is L2-backed so invisible in FETCH/WRITE). Macro expansion removes the
// escape so SROA can promote everything; waves_per_eu(2,2) gives the allocator the
// 256-VGPR budget. Zero arithmetic change -> bit-identical trajectory.
struct ScanSmem {
    u64   red[2][8];
    float EtabL[BB * BB];
    float EcTabL[BB * BB];
    float invSL[BB];
    float SL[BB];
    int   endL[BB];
    float invS_bc[2];
};
struct K3Smem2 {
    float Ws[64 * 65];
    float MsubA[64 * 65];
    float MsubB[64 * 65];
};
#define SMEM_BYTES ((sizeof(ScanSmem) > sizeof(K3Smem2)) ? sizeof(ScanSmem) : sizeof(K3Smem2))

#define SCAN_STEP(T, CUR, LD) {                                                         \
    const int t = (T);                                                                  \
    /* phase 0: wave0 early gathers (OLDEST vmem) */                                    \
    float grow_n = 0.f, pfx_n = 0.f, Ssc_n = 0.f, ecpf0 = 0.f;                          \
    if (w0 && t + 1 < BB) {                                                             \
        if (slot_act) ecpf0 = Ecold[(t + 1) * MM + slot_j];                             \
        grow_n = G[(t + 1) * BB + lane];                                                \
        pfx_n  = Pfx[(t + 1) * BB + lane];                                              \
        Ssc_n  = readlane_f(scold_r, t + 1);                                            \
    }                                                                                   \
    /* phase 1: combine 8 wave-partial argmins */                                       \
    int j0; float minval;                                                               \
    if (t == 0) { j0 = 0; minval = 0.f; }                                               \
    else {                                                                              \
        u64 pm = sm->red[t & 1][lane & 7];                                              \
        pm = wave_min8(pm);                                                             \
        j0 = (int)(pm & 0xFFFFFFFFu);                                                   \
        minval = __uint_as_float((unsigned)(pm >> 32));                                 \
    }                                                                                   \
    const float cuni_t = (t == 0) ? 0.f : cuni;                                         \
    float invS = w0 ? invS_reg : sm->invS_bc[t & 1];                                    \
    float latev = 0.f, ecpf_t = 0.f;                                                    \
    if (w0 && lane == t) {                                                              \
        latev = Ecold[t * MM + j0];                                                     \
        if (t + 1 < BB) ecpf_t = Ecold[(t + 1) * MM + j0];                              \
    }                                                                                   \
    __builtin_amdgcn_sched_barrier(0);                                                  \
    if (t + 2 < BB) {                                                                   \
        _Pragma("unroll")                                                               \
        for (int i = 0; i < K2C / 4; ++i) {                                             \
            float4 v = Ec4[(t + 2) * (MM / 4) + i * K2T + tid];                         \
            LD[4 * i + 0] = v.x; LD[4 * i + 1] = v.y;                                   \
            LD[4 * i + 2] = v.z; LD[4 * i + 3] = v.w;                                   \
        }                                                                               \
    }                                                                                   \
    __builtin_amdgcn_sched_barrier(0);                                                  \
    /* wave0: bookkeeping for t, lookahead for t+1 */                                   \
    bool fresh = false;                                                                 \
    if (w0) {                                                                           \
        u64 sup = __ballot(slot_act && (slot_j == j0));                                 \
        const bool has_sup = (sup != 0ull);                                             \
        const int  ssup = has_sup ? (int)__builtin_ctzll(sup) : 0;                      \
        if (slot_act) {                                                                 \
            float ww = cuni + ((t >= 2 && lane == t - 1) ? omb : 0.f);                  \
            wu_hot = fmaf(gamma, wu_hot, fmaf(e_true_c, invS, ww));                     \
        }                                                                               \
        float trans_wu = readlane_f(wu_hot, ssup);                                      \
        float trans_E  = readlane_f(e_true_c, ssup);                                    \
        if (lane == t) {                                                                \
            slot_j = j0;                                                                \
            float ww0 = cuni + ((t >= 1) ? omb : 0.f);                                  \
            slot_n2 = ww0 * ww0 * k2_cur;                                               \
            slot_act = true;                                                            \
            if (has_sup) wu_hot = trans_wu;                                             \
            fresh = !has_sup;                                                           \
        }                                                                               \
        if (has_sup) {                                                                  \
            if (lane == ssup) slot_act = false;                                         \
            if (lane == t) sm->endL[ssup] = t;                                          \
        }                                                                               \
        float etl = e_true_c, ecl = slot_ec;                                            \
        if (lane == t) { ecl = latev; etl = has_sup ? trans_E : latev; }                \
        sm->EtabL[t * BB + lane]  = etl;                                                \
        sm->EcTabL[t * BB + lane] = ecl;                                                \
        if (lane == 0) { sm->invSL[t] = invS; sm->SL[t] = S_reg; }                      \
        if (fresh) wu_hot = fmaf(gamma, minval, fmaf(latev, invS, cuni_t));             \
        if (t + 1 < BB) {                                                               \
            float d_ = cuni * pfx_n;                                                    \
            if (lane >= 1) d_ += omb * grow_n;                                          \
            float k2n   = readlane_f(grow_n, t + 1);                                    \
            float invkn = __builtin_amdgcn_rsqf(k2n);                                   \
            float ecpf  = (lane == t) ? ecpf_t : ecpf0;                                 \
            float myDelta = 0.f;                                                        \
            float e_n = 0.f;                                                            \
            if (slot_act) {                                                             \
                e_n = __expf(d_ * invkn * __builtin_amdgcn_rsqf(slot_n2));              \
                myDelta = e_n - ecpf;                                                   \
                slot_n2 = slot_n2 + 2.f * cuni * d_ + cuni * cuni * k2n;                \
            }                                                                           \
            float S_next = Ssc_n + wave_sum64(myDelta);                                 \
            float invS_next = __builtin_amdgcn_rcpf(S_next);                            \
            if (lane == 0) sm->invS_bc[(t + 1) & 1] = invS_next;                        \
            if (slot_act) slot_ec = ecpf;                                               \
            e_true_c = e_n;                                                             \
            k2_cur = k2n;                                                               \
            S_reg = S_next; invS_reg = invS_next;                                       \
        }                                                                               \
    }                                                                                   \
    /* all waves: cold w_u fma + first-index min over 16 cols */                        \
    float vmin = 0.f; int jmin = 0;                                                     \
    _Pragma("unroll")                                                                   \
    for (int i = 0; i < 4; ++i) {                                                       \
        _Pragma("unroll")                                                               \
        for (int q = 0; q < 4; ++q) {                                                   \
            int c = i * 4 + q;                                                          \
            float wun = fmaf(gamma, wu[c], fmaf(CUR[c], invS, cuni_t));                 \
            wu[c] = wun;                                                                \
            int j = i * 2048 + (tid << 2) + q;                                          \
            if (c == 0) { vmin = wun; jmin = j; }                                       \
            else if (wun < vmin) { vmin = wun; jmin = j; }                              \
        }                                                                               \
    }                                                                                   \
    u64 key = (((u64)__float_as_uint(vmin)) << 32) | (unsigned)jmin;                    \
    if (((j0 >> 2) & (K2T - 1)) == tid) {                                               \
        int cj = ((j0 >> 11) << 2) | (j0 & 3);                                          \
        _Pragma("unroll")                                                               \
        for (int c = 0; c < K2C; ++c) if (c == cj) wu[c] = __builtin_inff();            \
    }                                                                                   \
    if (w0) {                                                                           \
        u64 skey = (slot_act && !fresh)                                                 \
                 ? ((((u64)__float_as_uint(wu_hot)) << 32) | (unsigned)slot_j) : ~0ull; \
        key = skey < key ? skey : key;                                                  \
    }                                                                                   \
    key = wave_min64_lane63(key);                                                       \
    if (lane == 63) sm->red[(t + 1) & 1][wid] = key;                                    \
    asm volatile("s_waitcnt lgkmcnt(0)" ::: "memory");                                  \
    __builtin_amdgcn_s_barrier();                                                       \
    asm volatile("" ::: "memory");                                                      \
}

__global__ __launch_bounds__(512)
__attribute__((amdgpu_waves_per_eu(2, 2)))
void k23_scan_u1(const float* __restrict__ Ecold,
                 const float* __restrict__ G,
                 const float* __restrict__ Pfx,
                 const float* __restrict__ Spart,
                 const float* __restrict__ bp,
                 const float* __restrict__ gp,
                 const float* __restrict__ MK0,
                 float* __restrict__ Etab_g,
                 float* __restrict__ EcTab_g,
                 float* __restrict__ Sg,
                 float* __restrict__ invSg,
                 int*   __restrict__ endTab_g,
                 int*   __restrict__ hcolg,
                 float* __restrict__ parts) {
    __shared__ __align__(16) char smem_raw[SMEM_BYTES];
    const int tid = threadIdx.x;

    if (blockIdx.x != 0) {
        // ---------- double k3 tile (writes parts, exits) ----------
        K3Smem2* sm = (K3Smem2*)smem_raw;
        const int p = blockIdx.x - 1;      // 0..127
        const int by = p >> 2;             // 0..31
        const int half = tid >> 8;         // 0: waves 0-3, 1: waves 4-7
        const int g = tid & 255;
        const int d0 = (p & 3) * 128 + half * 64;
        const int lane = g & 63, w = g >> 6;
        const int t4 = ((w << 2) | (lane >> 4)) << 2;
        const int dq0 = lane & 15;
        float* Msub = half ? sm->MsubB : sm->MsubA;
        float acc[4][4];
        #pragma unroll
        for (int i = 0; i < 4; ++i)
            #pragma unroll
            for (int q = 0; q < 4; ++q) acc[i][q] = 0.f;
        for (int sub = 0; sub < 4; ++sub) {
            int jb = by * 256 + sub * 64;
            if (half == 0) {
                #pragma unroll
                for (int i = 0; i < 16; ++i) {
                    int e = i * 256 + g; int r = e >> 6, c = e & 63;
                    sm->Ws[r * 65 + c] = Ecold[r * MM + jb + c];
                    sm->MsubA[r * 65 + c] = MK0[(d0 + r) * MM + jb + c];
                }
            } else {
                #pragma unroll
                for (int i = 0; i < 16; ++i) {
                    int e = i * 256 + g; int r = e >> 6, c = e & 63;
                    sm->MsubB[r * 65 + c] = MK0[(d0 + r) * MM + jb + c];
                }
            }
            __syncthreads();
            #pragma unroll 4
            for (int jl = 0; jl < 64; ++jl) {
                float wv[4], mv[4];
                #pragma unroll
                for (int i = 0; i < 4; ++i) wv[i] = sm->Ws[(t4 + i) * 65 + jl];
                #pragma unroll
                for (int q = 0; q < 4; ++q) mv[q] = Msub[(dq0 + 16 * q) * 65 + jl];
                #pragma unroll
                for (int i = 0; i < 4; ++i)
                    #pragma unroll
                    for (int q = 0; q < 4; ++q) acc[i][q] += wv[i] * mv[q];
            }
            __syncthreads();
        }
        #pragma unroll
        for (int i = 0; i < 4; ++i)
            #pragma unroll
            for (int q = 0; q < 4; ++q)
                parts[(by * 64 + t4 + i) * DD + d0 + dq0 + 16 * q] = acc[i][q];
        return;
    }

    // ---------- block 0: the scan ----------
    ScanSmem* sm = (ScanSmem*)smem_raw;
    const int lane = tid & 63;
    const int wid = tid >> 6;
    const bool w0 = (wid == 0);

    const float beta  = 1.f / (1.f + expf(-bp[0]));
    const float gamma = gp[0];
    const float cuni  = beta / (float)MM;
    const float omb   = 1.f - beta;

    if (tid < BB) sm->endL[tid] = BB;

    const float4* Ec4 = reinterpret_cast<const float4*>(Ecold);

    float wu[K2C], e0[K2C], e1[K2C], e2[K2C];
    #pragma unroll
    for (int c = 0; c < K2C; ++c) wu[c] = 0.f;
    #pragma unroll
    for (int i = 0; i < K2C / 4; ++i) {
        float4 v = Ec4[i * K2T + tid];                  // row 0
        e0[4 * i + 0] = v.x; e0[4 * i + 1] = v.y; e0[4 * i + 2] = v.z; e0[4 * i + 3] = v.w;
        float4 u = Ec4[(MM / 4) + i * K2T + tid];       // row 1
        e1[4 * i + 0] = u.x; e1[4 * i + 1] = u.y; e1[4 * i + 2] = u.z; e1[4 * i + 3] = u.w;
    }

    // prologue: Scold[lane] = fixed-order sum over 128 block partials
    float scold_r = 0.f;
    if (w0) {
        const float4* sp4 = reinterpret_cast<const float4*>(Spart + lane * 128);
        float sc = 0.f;
        #pragma unroll 8
        for (int i = 0; i < 32; ++i) {
            float4 v = sp4[i];
            sc += v.x; sc += v.y; sc += v.z; sc += v.w;
        }
        scold_r = sc;
    }

    // slot state: WAVE 0 ONLY
    float slot_n2 = 0.f, slot_ec = 0.f, wu_hot = 0.f, e_true_c = 0.f;
    int   slot_j = -1;
    bool  slot_act = false;
    float k2_cur = 0.f, S_reg = 0.f, invS_reg = 0.f;

    if (w0) {
        float g0 = G[lane];
        k2_cur = readlane_f(g0, 0);      // G[0][0]
        S_reg = readlane_f(scold_r, 0);  // S(0): no active slots
        invS_reg = __builtin_amdgcn_rcpf(S_reg);
        if (lane == 0) sm->invS_bc[0] = invS_reg;
    }
    __syncthreads();

    #pragma unroll 1
    for (int th = 0; th < 63; th += 3) {
        SCAN_STEP(th + 0, e0, e2)
        SCAN_STEP(th + 1, e1, e0)
        SCAN_STEP(th + 2, e2, e1)
    }
    SCAN_STEP(63, e0, e2)

    // epilogue: dump logs
    for (int i = tid; i < BB * BB; i += K2T) {
        Etab_g[i]  = sm->EtabL[i];
        EcTab_g[i] = sm->EcTabL[i];
    }
    if (tid < BB) {
        Sg[tid] = sm->SL[tid];
        invSg[tid] = sm->invSL[tid];
        endTab_g[tid] = sm->endL[tid];
    }
    if (w0) hcolg[lane] = slot_j;
}

// ---------------- K3b: gather hot columns of MK0 into MKhot[s][d] ----------------
__global__ __launch_bounds__(512) void k3b_gather(const float* __restrict__ MK0, const int* __restrict__ hcolg,
                                                  float* __restrict__ MKhot) {
    int i = blockIdx.x, d = threadIdx.x;
    int h = hcolg[i];
    MKhot[i * DD + d] = MK0[d * MM + h];
}

// ---------------- K4: rebuild A/Dcol rows + final combine ----------------
__global__ __launch_bounds__(512) void k4_final(const float* __restrict__ parts,
                                                const float* __restrict__ K,
                                                const float* __restrict__ Etab,
                                                const float* __restrict__ EcTab,
                                                const int*   __restrict__ endTab,
                                                const float* __restrict__ Sg,
                                                const float* __restrict__ invSg,
                                                const float* __restrict__ MKhot,
                                                const float* __restrict__ bp,
                                                float* __restrict__ out) {
    __shared__ float Arow[BB];
    __shared__ float Drow[BB];
    int t = blockIdx.x, d = threadIdx.x;
    if (d < BB) {
        const float beta = 1.f / (1.f + expf(-bp[0]));
        const float cuni = beta / (float)MM;
        const float omb  = 1.f - beta;
        int s = d;
        float Ev = Etab[t * BB + s];
        int endv = endTab[s];
        bool act = (s <= t) && (t < endv);
        float S = Sg[t], invS = invSg[t];
        float ev = act ? Ev : 0.f;
        float x = ev;
        #pragma unroll
        for (int o = 1; o < 64; o <<= 1) {
            float y = __shfl_down(x, o);
            if (s + o < 64) x += y;
        }
        float suf = x - ev;
        float arow = 0.f;
        if (s < t) {
            float Qe = S - suf;
            arow = cuni * Qe;
            if (s >= 1 && act) arow += omb * Ev;
            arow *= invS;
        }
        Arow[s] = arow;
        Drow[s] = act ? (-invS * EcTab[t * BB + s]) : 0.f;
    }
    __syncthreads();
    float isv = invSg[t];
    float s1 = 0.f;
    #pragma unroll
    for (int p = 0; p < 32; ++p) s1 += parts[(p * 64 + t) * DD + d];
    float s2 = 0.f;
    for (int i = 0; i < BB; ++i) s2 += Drow[i] * MKhot[i * DD + d];
    float s3 = 0.f;
    for (int i = 0; i < BB; ++i) s3 += Arow[i] * K[i * DD + d];
    out[t * DD + d] = isv * s1 + s2 + s3;
}

extern "C" void kernel_launch(void* const* d_in, const int* in_sizes, int n_in,
                              void* d_out, int out_size, void* d_ws, size_t ws_size,
                              hipStream_t stream) {
    const float* K   = (const float*)d_in[0];   // k: [B,1,D]
    // d_in[1] = u: unused
    const float* MK0 = (const float*)d_in[2];   // memory_knowledge: [D,M]
    // d_in[3] = memory_understanding: unused
    const float* bp  = (const float*)d_in[4];   // beta_param
    const float* gp  = (const float*)d_in[5];   // memory_gamma

    float* ws    = (float*)d_ws;
    float* G     = ws;                  // 4096
    float* Pfx   = G + 4096;            // 4096
    float* Ecold = Pfx + 4096;          // 524288
    float* Spart = Ecold + 524288;      // 64*128 = 8192
    float* Etab  = Spart + 8192;        // 4096
    float* EcTab = Etab + 4096;         // 4096
    float* Sarr  = EcTab + 4096;        // 64
    float* invS  = Sarr + 64;           // 64
    float* MKhot = invS + 64;           // 32768
    float* parts = MKhot + 32768;       // 32*64*512 = 1048576
    int*   hcol  = (int*)(parts + 1048576);  // 64
    int*   endT  = hcol + 64;                // 64
    int*   flags = endT + 64;                // [0] = gram done
    float* out   = (float*)d_out;       // [B,1,D] f32

    hipMemsetAsync(flags, 0, sizeof(int), stream);
    kab_gram_ecold <<<129, 256, 0, stream>>>(K, MK0, bp, G, Pfx, Ecold, Spart, flags);
    k23_scan_u1    <<<129, 512, 0, stream>>>(Ecold, G, Pfx, Spart, bp, gp, MK0,
                                             Etab, EcTab, Sarr, invS, endT, hcol, parts);
    k3b_gather     <<<64, 512, 0, stream>>>(MK0, hcol, MKhot);
    k4_final       <<<64, 512, 0, stream>>>(parts, K, Etab, EcTab, endT, Sarr, invS, MKhot, bp, out);
}